// Round 4
// baseline (1007.698 us; speedup 1.0000x reference)
//
#include <hip/hip_runtime.h>
#include <math.h>

#define HIDDEN 2048
#define NHEADS 16
#define HD     128
#define QKV3   6144
#define EPSV   1e-5f

typedef short bf16x8 __attribute__((ext_vector_type(8)));
typedef float f32x4  __attribute__((ext_vector_type(4)));

__device__ inline unsigned short f2bf(float f) {
    unsigned u = __float_as_uint(f);
    u += 0x7fff + ((u >> 16) & 1);          // round-to-nearest-even
    return (unsigned short)(u >> 16);
}

union FragCast { uint4 u; bf16x8 v; };
__device__ inline bf16x8 as_frag(uint4 x) { FragCast c; c.u = x; return c.v; }

// ---------------- fp32 -> bf16 conversion (weights) ----------------
__global__ __launch_bounds__(256) void f32_to_bf16_kernel(
        const float* __restrict__ in, unsigned short* __restrict__ out, int count) {
    int i = (blockIdx.x * 256 + threadIdx.x) * 4;
    if (i >= count) return;
    float4 v = *(const float4*)&in[i];
    ushort4 o = {f2bf(v.x), f2bf(v.y), f2bf(v.z), f2bf(v.w)};
    *(ushort4*)&out[i] = o;
}

// ---------------- RoPE cos/sin table ----------------
__global__ void rope_table_kernel(float* __restrict__ cost, float* __restrict__ sint) {
    int pos = blockIdx.x;
    int i   = threadIdx.x;              // 0..63  (d//2 index)
    float inv = (float)pow(150000.0, -(double)i / 64.0);
    float f   = (float)pos * inv;
    cost[pos * 64 + i] = cosf(f);
    sint[pos * 64 + i] = sinf(f);
}

// ---------------- RMSNorm (fp32 in, bf16 out) ----------------
__global__ __launch_bounds__(256) void rmsnorm_kernel(
        const float* __restrict__ x, const float* __restrict__ scale,
        unsigned short* __restrict__ t) {
    int row = blockIdx.x;
    int tid = threadIdx.x;
    const float* xr = x + (size_t)row * HIDDEN;
    unsigned short* tr = t + (size_t)row * HIDDEN;

    float4 v[2];
    float ss = 0.f;
#pragma unroll
    for (int u = 0; u < 2; ++u) {
        v[u] = ((const float4*)xr)[tid + u * 256];
        ss += v[u].x * v[u].x + v[u].y * v[u].y + v[u].z * v[u].z + v[u].w * v[u].w;
    }
#pragma unroll
    for (int off = 32; off; off >>= 1) ss += __shfl_xor(ss, off);
    __shared__ float wsum[4];
    if ((tid & 63) == 0) wsum[tid >> 6] = ss;
    __syncthreads();
    float tot = wsum[0] + wsum[1] + wsum[2] + wsum[3];
    float r = rsqrtf(tot / (float)HIDDEN + EPSV);
#pragma unroll
    for (int u = 0; u < 2; ++u) {
        int idx = tid + u * 256;
        float4 sc = ((const float4*)scale)[idx];
        ushort4 o = {f2bf(v[u].x * r * sc.x), f2bf(v[u].y * r * sc.y),
                     f2bf(v[u].z * r * sc.z), f2bf(v[u].w * r * sc.w)};
        ((ushort4*)tr)[idx] = o;
    }
}

// ---------------- bf16 MFMA NT GEMM: C = A(MxK) * B(NxK)^T + bias (+resid) ----
// 128x128 tile, BK=32, 4 waves (2x2), wave tile 64x64 = 4x4 frags of 16x16x32.
__global__ __launch_bounds__(256) void gemm_bf16_kernel(
        const unsigned short* __restrict__ A, const unsigned short* __restrict__ B,
        const float* __restrict__ bias, const float* __restrict__ resid,
        float* __restrict__ C, int M, int N, int K) {
    __shared__ __align__(16) unsigned short As[128][32];
    __shared__ __align__(16) unsigned short Bs[128][32];

    int tid  = threadIdx.x;
    int bn   = blockIdx.x * 128;
    int bm   = blockIdx.y * 128;
    int lane = tid & 63;
    int wid  = tid >> 6;
    int wr   = wid >> 1;           // 0..1
    int wc   = wid & 1;            // 0..1
    int fr   = lane & 15;          // fragment row/col index
    int fq   = lane >> 4;          // 0..3  k-group / row-group

    f32x4 acc[4][4] = {};

    const int nk = K >> 5;
    for (int kt = 0; kt < nk; ++kt) {
        int k0 = kt << 5;
        // stage A,B tiles: 512 chunks of 16B each per tile, 2 per thread
#pragma unroll
        for (int u = 0; u < 2; ++u) {
            int c   = tid + u * 256;
            int row = c >> 2;
            int kk  = (c & 3) * 8;
            *(uint4*)&As[row][kk] = *(const uint4*)&A[(size_t)(bm + row) * K + k0 + kk];
            *(uint4*)&Bs[row][kk] = *(const uint4*)&B[(size_t)(bn + row) * K + k0 + kk];
        }
        __syncthreads();

        bf16x8 af[4], bfr[4];
#pragma unroll
        for (int i = 0; i < 4; ++i) {
            af[i]  = as_frag(*(const uint4*)&As[wr * 64 + i * 16 + fr][fq * 8]);
            bfr[i] = as_frag(*(const uint4*)&Bs[wc * 64 + i * 16 + fr][fq * 8]);
        }
#pragma unroll
        for (int mi = 0; mi < 4; ++mi)
#pragma unroll
            for (int ni = 0; ni < 4; ++ni)
                acc[mi][ni] = __builtin_amdgcn_mfma_f32_16x16x32_bf16(
                    af[mi], bfr[ni], acc[mi][ni], 0, 0, 0);
        __syncthreads();
    }

    // epilogue: D[row][col] with col = lane&15, row = 4*(lane>>4)+r
#pragma unroll
    for (int ni = 0; ni < 4; ++ni) {
        int col = bn + wc * 64 + ni * 16 + fr;
        float bb = bias[col];
#pragma unroll
        for (int mi = 0; mi < 4; ++mi) {
#pragma unroll
            for (int r = 0; r < 4; ++r) {
                int row = bm + wr * 64 + mi * 16 + fq * 4 + r;
                float v = acc[mi][ni][r] + bb;
                if (resid) v += resid[(size_t)row * N + col];
                C[(size_t)row * N + col] = v;
            }
        }
    }
}

// ---------------- RoPE apply (in-place on q,k parts of qkv, fp32) ----------------
__global__ void rope_apply_kernel(float* __restrict__ qkv,
                                  const float* __restrict__ cost,
                                  const float* __restrict__ sint) {
    int pos  = blockIdx.x;
    int part = blockIdx.y;           // head*2 + (0=q,1=k)
    int head = part >> 1;
    int qk   = part & 1;
    int i    = threadIdx.x;          // 0..63
    float* base = qkv + (size_t)pos * QKV3 + qk * HIDDEN + head * HD;
    float c = cost[pos * 64 + i];
    float s = sint[pos * 64 + i];
    float x1 = base[i];
    float x2 = base[i + 64];
    base[i]      = x1 * c - x2 * s;
    base[i + 64] = x2 * c + x1 * s;
}

// ---------------- flash-style causal attention (fp32 math, bf16 output) -------
// grid: (n/64, NHEADS), block 256. Q tile 64 rows, K/V tiles 32 rows.
__global__ __launch_bounds__(256) void attn_kernel(
        const float* __restrict__ qkv, unsigned short* __restrict__ o, int n) {
    int h  = blockIdx.y;
    int q0 = blockIdx.x * 64;
    int tid = threadIdx.x;

    __shared__ __align__(16) float Qs[HD][64];   // [d][m]   32 KB
    __shared__ __align__(16) float Ks[HD][32];   // [d][c]   16 KB
    __shared__ __align__(16) float Vs[32][HD];   // [c][d]   16 KB
    __shared__ __align__(16) float Sl[64][33];   //          8.4 KB
    __shared__ float mrow[64], lrow[64], rscale[64];

#pragma unroll
    for (int u = 0; u < 8; ++u) {
        int f = tid + u * 256;
        int row = f >> 5;
        int c = (f & 31) * 4;
        float4 qv = *(const float4*)&qkv[(size_t)(q0 + row) * QKV3 + h * HD + c];
        Qs[c + 0][row] = qv.x; Qs[c + 1][row] = qv.y;
        Qs[c + 2][row] = qv.z; Qs[c + 3][row] = qv.w;
    }
    if (tid < 64) { mrow[tid] = -INFINITY; lrow[tid] = 0.f; }
    float oacc[4][8] = {};
    __syncthreads();

    int ktmax = (q0 + 63) >> 5;
    for (int kt = 0; kt <= ktmax; ++kt) {
        int k0 = kt * 32;
#pragma unroll
        for (int u = 0; u < 4; ++u) {
            int f = tid + u * 256;
            int row = f >> 5;                    // 0..31
            int c = (f & 31) * 4;
            float4 kv = *(const float4*)&qkv[(size_t)(k0 + row) * QKV3 + HIDDEN + h * HD + c];
            Ks[c + 0][row] = kv.x; Ks[c + 1][row] = kv.y;
            Ks[c + 2][row] = kv.z; Ks[c + 3][row] = kv.w;
            float4 vv = *(const float4*)&qkv[(size_t)(k0 + row) * QKV3 + 2 * HIDDEN + h * HD + c];
            *(float4*)&Vs[row][c] = vv;
        }
        __syncthreads();

        {
            int r0 = (tid >> 3) * 2;
            int cS = (tid & 7) * 4;
            float s00 = 0, s01 = 0, s02 = 0, s03 = 0;
            float s10 = 0, s11 = 0, s12 = 0, s13 = 0;
#pragma unroll 4
            for (int d = 0; d < HD; ++d) {
                float2 a2 = *(const float2*)&Qs[d][r0];
                float4 b4 = *(const float4*)&Ks[d][cS];
                s00 = fmaf(a2.x, b4.x, s00);
                s01 = fmaf(a2.x, b4.y, s01);
                s02 = fmaf(a2.x, b4.z, s02);
                s03 = fmaf(a2.x, b4.w, s03);
                s10 = fmaf(a2.y, b4.x, s10);
                s11 = fmaf(a2.y, b4.y, s11);
                s12 = fmaf(a2.y, b4.z, s12);
                s13 = fmaf(a2.y, b4.w, s13);
            }
            const float sc = 0.088388347648318447f;  // 1/sqrt(128)
            int qi0 = q0 + r0, qi1 = qi0 + 1;
            Sl[r0 + 0][cS + 0] = (k0 + cS + 0 <= qi0) ? s00 * sc : -INFINITY;
            Sl[r0 + 0][cS + 1] = (k0 + cS + 1 <= qi0) ? s01 * sc : -INFINITY;
            Sl[r0 + 0][cS + 2] = (k0 + cS + 2 <= qi0) ? s02 * sc : -INFINITY;
            Sl[r0 + 0][cS + 3] = (k0 + cS + 3 <= qi0) ? s03 * sc : -INFINITY;
            Sl[r0 + 1][cS + 0] = (k0 + cS + 0 <= qi1) ? s10 * sc : -INFINITY;
            Sl[r0 + 1][cS + 1] = (k0 + cS + 1 <= qi1) ? s11 * sc : -INFINITY;
            Sl[r0 + 1][cS + 2] = (k0 + cS + 2 <= qi1) ? s12 * sc : -INFINITY;
            Sl[r0 + 1][cS + 3] = (k0 + cS + 3 <= qi1) ? s13 * sc : -INFINITY;
        }
        __syncthreads();

        if (tid < 64) {
            int r = tid;
            float m_old = mrow[r];
            float mx = m_old;
            for (int c = 0; c < 32; ++c) mx = fmaxf(mx, Sl[r][c]);
            float sum = 0.f;
            for (int c = 0; c < 32; ++c) {
                float p = expf(Sl[r][c] - mx);
                Sl[r][c] = p;
                sum += p;
            }
            float sc = expf(m_old - mx);
            rscale[r] = sc;
            lrow[r] = lrow[r] * sc + sum;
            mrow[r] = mx;
        }
        __syncthreads();

        {
            int r0 = (tid >> 4) * 4;
            int cA = (tid & 15) * 4;
#pragma unroll
            for (int i = 0; i < 4; ++i) {
                float sc = rscale[r0 + i];
#pragma unroll
                for (int j = 0; j < 8; ++j) oacc[i][j] *= sc;
            }
#pragma unroll 2
            for (int kk = 0; kk < 32; ++kk) {
                float pp[4];
#pragma unroll
                for (int i = 0; i < 4; ++i) pp[i] = Sl[r0 + i][kk];
                float4 v0 = *(const float4*)&Vs[kk][cA];
                float4 v1 = *(const float4*)&Vs[kk][64 + cA];
                float vv[8] = {v0.x, v0.y, v0.z, v0.w, v1.x, v1.y, v1.z, v1.w};
#pragma unroll
                for (int i = 0; i < 4; ++i)
#pragma unroll
                    for (int j = 0; j < 8; ++j)
                        oacc[i][j] = fmaf(pp[i], vv[j], oacc[i][j]);
            }
        }
        __syncthreads();
    }

    {
        int r0 = (tid >> 4) * 4;
        int cA = (tid & 15) * 4;
#pragma unroll
        for (int i = 0; i < 4; ++i) {
            float inv = 1.0f / lrow[r0 + i];
            ushort4 w0 = {f2bf(oacc[i][0] * inv), f2bf(oacc[i][1] * inv),
                          f2bf(oacc[i][2] * inv), f2bf(oacc[i][3] * inv)};
            ushort4 w1 = {f2bf(oacc[i][4] * inv), f2bf(oacc[i][5] * inv),
                          f2bf(oacc[i][6] * inv), f2bf(oacc[i][7] * inv)};
            *(ushort4*)&o[(size_t)(q0 + r0 + i) * HIDDEN + h * HD + cA] = w0;
            *(ushort4*)&o[(size_t)(q0 + r0 + i) * HIDDEN + h * HD + 64 + cA] = w1;
        }
    }
}

extern "C" void kernel_launch(void* const* d_in, const int* in_sizes, int n_in,
                              void* d_out, int out_size, void* d_ws, size_t ws_size,
                              hipStream_t stream) {
    const float* x     = (const float*)d_in[0];
    const float* nsc   = (const float*)d_in[1];
    const float* qkv_w = (const float*)d_in[2];
    const float* qkv_b = (const float*)d_in[3];
    const float* out_w = (const float*)d_in[4];
    const float* out_b = (const float*)d_in[5];
    float* out = (float*)d_out;
    int n = in_sizes[0] / HIDDEN;     // 2048

    // Workspace layout (bytes). tb (rmsnorm bf16 out) dead after GEMM1 ->
    // aliases ob (attention bf16 out). Total ~93 MB.
    char* w = (char*)d_ws;
    float* qkv = (float*)w;                 w += (size_t)n * QKV3 * 4;      // 50.3 MB
    float* cost = (float*)w;                w += (size_t)n * 64 * 4;
    float* sint = (float*)w;                w += (size_t)n * 64 * 4;
    unsigned short* wq = (unsigned short*)w; w += (size_t)QKV3 * HIDDEN * 2; // 25.2 MB
    unsigned short* wo = (unsigned short*)w; w += (size_t)HIDDEN * HIDDEN * 2; // 8.4 MB
    unsigned short* tb = (unsigned short*)w;                                 // 8.4 MB
    unsigned short* ob = tb;                                                 // aliased

    f32_to_bf16_kernel<<<(QKV3 * HIDDEN) / 1024, 256, 0, stream>>>(qkv_w, wq, QKV3 * HIDDEN);
    f32_to_bf16_kernel<<<(HIDDEN * HIDDEN) / 1024, 256, 0, stream>>>(out_w, wo, HIDDEN * HIDDEN);
    rope_table_kernel<<<n, 64, 0, stream>>>(cost, sint);
    rmsnorm_kernel<<<n, 256, 0, stream>>>(x, nsc, tb);
    gemm_bf16_kernel<<<dim3(QKV3 / 128, n / 128), 256, 0, stream>>>(
        tb, wq, qkv_b, nullptr, qkv, n, QKV3, HIDDEN);
    rope_apply_kernel<<<dim3(n, 2 * NHEADS), 64, 0, stream>>>(qkv, cost, sint);
    attn_kernel<<<dim3(n / 64, NHEADS), 256, 0, stream>>>(qkv, ob, n);
    gemm_bf16_kernel<<<dim3(HIDDEN / 128, n / 128), 256, 0, stream>>>(
        ob, wo, out_b, x, out, n, HIDDEN, HIDDEN);
}

// Round 7
// 357.463 us; speedup vs baseline: 2.8190x; 2.8190x over previous
//
#include <hip/hip_runtime.h>
#include <math.h>

#define HIDDEN 2048
#define NHEADS 16
#define HD     128
#define QKV3   6144
#define EPSV   1e-5f
#define NEGBIG -30000.0f

typedef short bf16x8 __attribute__((ext_vector_type(8)));
typedef float f32x4  __attribute__((ext_vector_type(4)));

__device__ inline unsigned short f2bf(float f) {
    unsigned u = __float_as_uint(f);
    u += 0x7fff + ((u >> 16) & 1);          // round-to-nearest-even
    return (unsigned short)(u >> 16);
}

union FragCast { uint4 u; bf16x8 v; };
__device__ inline bf16x8 as_frag(uint4 x) { FragCast c; c.u = x; return c.v; }
union U16x8 { unsigned short h[8]; uint4 v; };

// ---------------- fp32 -> bf16 conversion (weights) ----------------
__global__ __launch_bounds__(256) void f32_to_bf16_kernel(
        const float* __restrict__ in, unsigned short* __restrict__ out, int count) {
    int i = (blockIdx.x * 256 + threadIdx.x) * 4;
    if (i >= count) return;
    float4 v = *(const float4*)&in[i];
    ushort4 o = {f2bf(v.x), f2bf(v.y), f2bf(v.z), f2bf(v.w)};
    *(ushort4*)&out[i] = o;
}

// ---------------- RoPE cos/sin table ----------------
__global__ void rope_table_kernel(float* __restrict__ cost, float* __restrict__ sint) {
    int pos = blockIdx.x;
    int i   = threadIdx.x;              // 0..63  (d//2 index)
    float inv = (float)pow(150000.0, -(double)i / 64.0);
    float f   = (float)pos * inv;
    cost[pos * 64 + i] = cosf(f);
    sint[pos * 64 + i] = sinf(f);
}

// ---------------- RMSNorm (fp32 in, bf16 out) ----------------
__global__ __launch_bounds__(256) void rmsnorm_kernel(
        const float* __restrict__ x, const float* __restrict__ scale,
        unsigned short* __restrict__ t) {
    int row = blockIdx.x;
    int tid = threadIdx.x;
    const float* xr = x + (size_t)row * HIDDEN;
    unsigned short* tr = t + (size_t)row * HIDDEN;

    float4 v[2];
    float ss = 0.f;
#pragma unroll
    for (int u = 0; u < 2; ++u) {
        v[u] = ((const float4*)xr)[tid + u * 256];
        ss += v[u].x * v[u].x + v[u].y * v[u].y + v[u].z * v[u].z + v[u].w * v[u].w;
    }
#pragma unroll
    for (int off = 32; off; off >>= 1) ss += __shfl_xor(ss, off);
    __shared__ float wsum[4];
    if ((tid & 63) == 0) wsum[tid >> 6] = ss;
    __syncthreads();
    float tot = wsum[0] + wsum[1] + wsum[2] + wsum[3];
    float r = rsqrtf(tot / (float)HIDDEN + EPSV);
#pragma unroll
    for (int u = 0; u < 2; ++u) {
        int idx = tid + u * 256;
        float4 sc = ((const float4*)scale)[idx];
        ushort4 o = {f2bf(v[u].x * r * sc.x), f2bf(v[u].y * r * sc.y),
                     f2bf(v[u].z * r * sc.z), f2bf(v[u].w * r * sc.w)};
        ((ushort4*)tr)[idx] = o;
    }
}

// ---------------- bf16 MFMA NT GEMM: C = A(MxK) * B(NxK)^T + bias (+resid) ----
// 128x128 tile, BK=32, 4 waves (2x2), wave tile 64x64 = 4x4 frags of 16x16x32.
__global__ __launch_bounds__(256) void gemm_bf16_kernel(
        const unsigned short* __restrict__ A, const unsigned short* __restrict__ B,
        const float* __restrict__ bias, const float* __restrict__ resid,
        float* __restrict__ C, int M, int N, int K) {
    __shared__ __align__(16) unsigned short As[128][32];
    __shared__ __align__(16) unsigned short Bs[128][32];

    int tid  = threadIdx.x;
    int bn   = blockIdx.x * 128;
    int bm   = blockIdx.y * 128;
    int lane = tid & 63;
    int wid  = tid >> 6;
    int wr   = wid >> 1;           // 0..1
    int wc   = wid & 1;            // 0..1
    int fr   = lane & 15;          // fragment row/col index
    int fq   = lane >> 4;          // 0..3  k-group / row-group

    f32x4 acc[4][4] = {};

    const int nk = K >> 5;
    for (int kt = 0; kt < nk; ++kt) {
        int k0 = kt << 5;
#pragma unroll
        for (int u = 0; u < 2; ++u) {
            int c   = tid + u * 256;
            int row = c >> 2;
            int kk  = (c & 3) * 8;
            *(uint4*)&As[row][kk] = *(const uint4*)&A[(size_t)(bm + row) * K + k0 + kk];
            *(uint4*)&Bs[row][kk] = *(const uint4*)&B[(size_t)(bn + row) * K + k0 + kk];
        }
        __syncthreads();

        bf16x8 af[4], bfr[4];
#pragma unroll
        for (int i = 0; i < 4; ++i) {
            af[i]  = as_frag(*(const uint4*)&As[wr * 64 + i * 16 + fr][fq * 8]);
            bfr[i] = as_frag(*(const uint4*)&Bs[wc * 64 + i * 16 + fr][fq * 8]);
        }
#pragma unroll
        for (int mi = 0; mi < 4; ++mi)
#pragma unroll
            for (int ni = 0; ni < 4; ++ni)
                acc[mi][ni] = __builtin_amdgcn_mfma_f32_16x16x32_bf16(
                    af[mi], bfr[ni], acc[mi][ni], 0, 0, 0);
        __syncthreads();
    }

#pragma unroll
    for (int ni = 0; ni < 4; ++ni) {
        int col = bn + wc * 64 + ni * 16 + fr;
        float bb = bias[col];
#pragma unroll
        for (int mi = 0; mi < 4; ++mi) {
#pragma unroll
            for (int r = 0; r < 4; ++r) {
                int row = bm + wr * 64 + mi * 16 + fq * 4 + r;
                float v = acc[mi][ni][r] + bb;
                if (resid) v += resid[(size_t)row * N + col];
                C[(size_t)row * N + col] = v;
            }
        }
    }
}

// ---------------- repack q,k: RoPE + bf16 + q pre-scale ----------------
// grid (n, NHEADS), block 128: threads 0-63 -> q, 64-127 -> k
__global__ void repack_qk_kernel(const float* __restrict__ qkv,
                                 const float* __restrict__ cost,
                                 const float* __restrict__ sint,
                                 unsigned short* __restrict__ qb,
                                 unsigned short* __restrict__ kb, int n) {
    int pos = blockIdx.x, h = blockIdx.y;
    int t = threadIdx.x;
    int qk = t >> 6, i = t & 63;
    const float* src = qkv + (size_t)pos * QKV3 + qk * HIDDEN + h * HD;
    float c = cost[pos * 64 + i], s = sint[pos * 64 + i];
    float x1 = src[i], x2 = src[i + 64];
    float y1 = x1 * c - x2 * s, y2 = x2 * c + x1 * s;
    float sc = qk ? 1.0f : 0.088388347648318447f;     // q pre-scaled by 1/sqrt(128)
    unsigned short* dst = (qk ? kb : qb) + ((size_t)h * n + pos) * HD;
    dst[i]      = f2bf(y1 * sc);
    dst[i + 64] = f2bf(y2 * sc);
}

// ---------------- V transpose: qkv fp32 v-part -> vt[h][d][n] bf16 ----------------
// grid (n/64, HD/64, NHEADS), block 256
__global__ __launch_bounds__(256) void v_transpose_kernel(
        const float* __restrict__ qkv, unsigned short* __restrict__ vt, int n) {
    int n0 = blockIdx.x * 64;
    int d0 = blockIdx.y * 64;
    int h  = blockIdx.z;
    __shared__ float tile[64][68];
    int tid = threadIdx.x;
#pragma unroll
    for (int u = 0; u < 4; ++u) {
        int c = tid + u * 256;             // 0..1023
        int r = c >> 4, c4 = (c & 15) * 4;
        *(float4*)&tile[r][c4] =
            *(const float4*)&qkv[(size_t)(n0 + r) * QKV3 + 2 * HIDDEN + h * HD + d0 + c4];
    }
    __syncthreads();
#pragma unroll
    for (int u = 0; u < 2; ++u) {
        int c = tid + u * 256;             // 0..511
        int d = c >> 3, nn = (c & 7) * 8;
        U16x8 o;
#pragma unroll
        for (int e = 0; e < 8; ++e) o.h[e] = f2bf(tile[nn + e][d]);
        *(uint4*)&vt[((size_t)h * HD + d0 + d) * n + n0 + nn] = o.v;
    }
}

// ---------------- MFMA flash attention ----------------
// grid (n/64, NHEADS), block 256 (4 waves x 16 q-rows). KV tile 64.
#define KVB 64
__global__ __launch_bounds__(256) void attn_mfma_kernel(
        const unsigned short* __restrict__ qb,   // [H][n][128] bf16 (pre-scaled)
        const unsigned short* __restrict__ kb,   // [H][n][128] bf16
        const unsigned short* __restrict__ vt,   // [H][128][n] bf16
        unsigned short* __restrict__ ob, int n) {
    int h   = blockIdx.y;
    int qbi = gridDim.x - 1 - blockIdx.x;        // long-running blocks first
    int q0  = qbi * 64;
    int tid = threadIdx.x;
    int lane = tid & 63, w = tid >> 6;
    int g = lane >> 4, i = lane & 15;

    __shared__ __align__(16) unsigned short Kb[KVB][136];   // +8 pad
    __shared__ __align__(16) unsigned short Vt[128][72];
    __shared__ __align__(16) unsigned short Pl[4][16][72];

    // Q fragments (A layout): rows q0+w*16+i, k-dim d
    bf16x8 qf[4];
    {
        const unsigned short* qrow = qb + ((size_t)h * n + q0 + w * 16 + i) * HD;
#pragma unroll
        for (int kk = 0; kk < 4; ++kk)
            qf[kk] = as_frag(*(const uint4*)&qrow[kk * 32 + 8 * g]);
    }

    f32x4 o_acc[8] = {};
    float m_r[4], l_r[4];
    // m init 0 (finite): alpha on first tile multiplies o=0,l=0 so any finite
    // init is exact; 0-floored running max keeps all exp args in [-6e4, 0].
#pragma unroll
    for (int r = 0; r < 4; ++r) { m_r[r] = 0.f; l_r[r] = 0.f; }

    int ntiles = q0 / KVB + 1;
    for (int kt = 0; kt < ntiles; ++kt) {
        int k0 = kt * KVB;
        // stage K tile: 64 rows x 128 d = 1024 16B chunks (4 iters x 256 thr)
#pragma unroll
        for (int u = 0; u < 4; ++u) {
            int c = tid + u * 256;             // 0..1023
            int row = c >> 4, col = (c & 15) * 8;
            *(uint4*)&Kb[row][col] =
                *(const uint4*)&kb[((size_t)h * n + k0 + row) * HD + col];
        }
        // stage V^T tile: 128 rows x 64 k = 1024 16B chunks
#pragma unroll
        for (int u = 0; u < 4; ++u) {
            int c = tid + u * 256;             // 0..1023
            int row = c >> 3, col = (c & 7) * 8;
            *(uint4*)&Vt[row][col] =
                *(const uint4*)&vt[((size_t)h * HD + row) * n + k0 + col];
        }
        __syncthreads();

        // QK^T: s_acc[nb] -> S[q=4g+r][k=nb*16+i]
        f32x4 s_acc[4] = {};
#pragma unroll
        for (int nb = 0; nb < 4; ++nb)
#pragma unroll
            for (int kk = 0; kk < 4; ++kk) {
                bf16x8 kf = as_frag(*(const uint4*)&Kb[nb * 16 + i][kk * 32 + 8 * g]);
                s_acc[nb] = __builtin_amdgcn_mfma_f32_16x16x32_bf16(
                    qf[kk], kf, s_acc[nb], 0, 0, 0);
            }

        // causal mask (diagonal tile only) + row max
        bool diag = (kt == ntiles - 1);
        float mx[4];
#pragma unroll
        for (int r = 0; r < 4; ++r) mx[r] = NEGBIG;
#pragma unroll
        for (int nb = 0; nb < 4; ++nb)
#pragma unroll
            for (int r = 0; r < 4; ++r) {
                float s = s_acc[nb][r];
                if (diag && (k0 + nb * 16 + i > q0 + w * 16 + 4 * g + r)) s = NEGBIG;
                s_acc[nb][r] = s;
                mx[r] = fmaxf(mx[r], s);
            }
#pragma unroll
        for (int off = 1; off < 16; off <<= 1)
#pragma unroll
            for (int r = 0; r < 4; ++r)
                mx[r] = fmaxf(mx[r], __shfl_xor(mx[r], off));

        float alpha[4], sum[4];
#pragma unroll
        for (int r = 0; r < 4; ++r) {
            float mnew = fmaxf(m_r[r], mx[r]);
            alpha[r] = expf(m_r[r] - mnew);
            m_r[r] = mnew;
            sum[r] = 0.f;
        }
#pragma unroll
        for (int nb = 0; nb < 4; ++nb)
#pragma unroll
            for (int r = 0; r < 4; ++r) {
                float p = expf(s_acc[nb][r] - m_r[r]);
                s_acc[nb][r] = p;
                sum[r] += p;
            }
#pragma unroll
        for (int off = 1; off < 16; off <<= 1)
#pragma unroll
            for (int r = 0; r < 4; ++r)
                sum[r] += __shfl_xor(sum[r], off);
#pragma unroll
        for (int r = 0; r < 4; ++r) l_r[r] = l_r[r] * alpha[r] + sum[r];

        // rescale O
#pragma unroll
        for (int d0 = 0; d0 < 8; ++d0)
#pragma unroll
            for (int r = 0; r < 4; ++r)
                o_acc[d0][r] *= alpha[r];

        // P -> LDS (bf16), D-layout -> A-layout transpose
#pragma unroll
        for (int nb = 0; nb < 4; ++nb)
#pragma unroll
            for (int r = 0; r < 4; ++r)
                Pl[w][4 * g + r][nb * 16 + i] = f2bf(s_acc[nb][r]);
        __syncthreads();   // hard ordering of P writes vs PV reads

        // PV: o_acc[d0] += P(16xKVB) * V(KVBx16)
#pragma unroll
        for (int kk = 0; kk < 2; ++kk) {
            bf16x8 pf = as_frag(*(const uint4*)&Pl[w][i][kk * 32 + 8 * g]);
#pragma unroll
            for (int d0 = 0; d0 < 8; ++d0) {
                bf16x8 vf = as_frag(*(const uint4*)&Vt[d0 * 16 + i][kk * 32 + 8 * g]);
                o_acc[d0] = __builtin_amdgcn_mfma_f32_16x16x32_bf16(
                    pf, vf, o_acc[d0], 0, 0, 0);
            }
        }
        __syncthreads();
    }

    // epilogue: divide by l, write bf16
#pragma unroll
    for (int r = 0; r < 4; ++r) {
        float inv = 1.f / l_r[r];
        int row = q0 + w * 16 + 4 * g + r;
#pragma unroll
        for (int d0 = 0; d0 < 8; ++d0)
            ob[(size_t)row * HIDDEN + h * HD + d0 * 16 + i] = f2bf(o_acc[d0][r] * inv);
    }
}

extern "C" void kernel_launch(void* const* d_in, const int* in_sizes, int n_in,
                              void* d_out, int out_size, void* d_ws, size_t ws_size,
                              hipStream_t stream) {
    const float* x     = (const float*)d_in[0];
    const float* nsc   = (const float*)d_in[1];
    const float* qkv_w = (const float*)d_in[2];
    const float* qkv_b = (const float*)d_in[3];
    const float* out_w = (const float*)d_in[4];
    const float* out_b = (const float*)d_in[5];
    float* out = (float*)d_out;
    int n = in_sizes[0] / HIDDEN;     // 2048

    // Workspace (~93 MB, proven size). wq region is dead after GEMM1 and is
    // reused for qb/kb/vt (3*n*HIDDEN*2 == QKV3*HIDDEN*2 at n=2048).
    char* w = (char*)d_ws;
    float* qkv  = (float*)w;  w += (size_t)n * QKV3 * 4;
    float* cost = (float*)w;  w += (size_t)n * 64 * 4;
    float* sint = (float*)w;  w += (size_t)n * 64 * 4;
    unsigned short* wq = (unsigned short*)w;
    unsigned short* qb = wq;
    unsigned short* kb = qb + (size_t)n * HIDDEN;
    unsigned short* vt = kb + (size_t)n * HIDDEN;
    size_t unionBytes = (size_t)QKV3 * HIDDEN * 2;
    size_t need3      = (size_t)3 * n * HIDDEN * 2;
    w += (unionBytes > need3 ? unionBytes : need3);
    unsigned short* wo = (unsigned short*)w;  w += (size_t)HIDDEN * HIDDEN * 2;
    unsigned short* tb = (unsigned short*)w;             // rmsnorm out (bf16)
    unsigned short* ob = tb;                             // attn out aliases tb

    f32_to_bf16_kernel<<<(QKV3 * HIDDEN) / 1024, 256, 0, stream>>>(qkv_w, wq, QKV3 * HIDDEN);
    f32_to_bf16_kernel<<<(HIDDEN * HIDDEN) / 1024, 256, 0, stream>>>(out_w, wo, HIDDEN * HIDDEN);
    rope_table_kernel<<<n, 64, 0, stream>>>(cost, sint);
    rmsnorm_kernel<<<n, 256, 0, stream>>>(x, nsc, tb);
    gemm_bf16_kernel<<<dim3(QKV3 / 128, n / 128), 256, 0, stream>>>(
        tb, wq, qkv_b, nullptr, qkv, n, QKV3, HIDDEN);
    repack_qk_kernel<<<dim3(n, NHEADS), 128, 0, stream>>>(qkv, cost, sint, qb, kb, n);
    v_transpose_kernel<<<dim3(n / 64, HD / 64, NHEADS), 256, 0, stream>>>(qkv, vt, n);
    attn_mfma_kernel<<<dim3(n / 64, NHEADS), 256, 0, stream>>>(qb, kb, vt, ob, n);
    gemm_bf16_kernel<<<dim3(HIDDEN / 128, n / 128), 256, 0, stream>>>(
        ob, wo, out_b, x, out, n, HIDDEN, HIDDEN);
}